// Round 7
// baseline (191.979 us; speedup 1.0000x reference)
//
#include <hip/hip_runtime.h>
#include <stdint.h>

#define C_DIM 8192
#define O_DIM 8192
#define M_DIM 256
#define NG    128     // C/64 groups
#define RK    32

typedef float f32x4 __attribute__((ext_vector_type(4)));
typedef int   i32x4 __attribute__((ext_vector_type(4)));
typedef unsigned int u32;

__device__ __forceinline__ void gll4(const void* g, void* l) {
  __builtin_amdgcn_global_load_lds(
      (const __attribute__((address_space(1))) void*)g,
      (__attribute__((address_space(3))) void*)l, 4, 0, 0);
}

// ---------------------------------------------------------------------------
// k_lora: lact[m][r] = sum_k x[m][k] * pd[k][r]   (256 x 32, f32)
// ---------------------------------------------------------------------------
__global__ __launch_bounds__(256) void k_lora(const float* __restrict__ x,
                                              const float* __restrict__ pd,
                                              float* __restrict__ lact) {
  const int t  = threadIdx.x;
  const int rq = t & 7;           // r-quad fastest -> coalesced pd
  const int kc = (t >> 3) & 15;
  const int ml = t >> 7;
  const int m  = blockIdx.x * 2 + ml;
  const float* xrow = x + (size_t)m * C_DIM + kc * 512;
  const float* pdp  = pd + (size_t)(kc * 512) * RK + rq * 4;
  float a0 = 0.f, a1 = 0.f, a2 = 0.f, a3 = 0.f;
  for (int k = 0; k < 512; k += 4) {
    float4 xv = *(const float4*)(xrow + k);
    float4 p0 = *(const float4*)(pdp + (size_t)(k + 0) * RK);
    float4 p1 = *(const float4*)(pdp + (size_t)(k + 1) * RK);
    float4 p2 = *(const float4*)(pdp + (size_t)(k + 2) * RK);
    float4 p3 = *(const float4*)(pdp + (size_t)(k + 3) * RK);
    a0 += xv.x * p0.x + xv.y * p1.x + xv.z * p2.x + xv.w * p3.x;
    a1 += xv.x * p0.y + xv.y * p1.y + xv.z * p2.y + xv.w * p3.y;
    a2 += xv.x * p0.z + xv.y * p1.z + xv.z * p2.z + xv.w * p3.z;
    a3 += xv.x * p0.w + xv.y * p1.w + xv.z * p2.w + xv.w * p3.w;
  }
  __shared__ float red[2][8][16][4];
  red[ml][rq][kc][0] = a0;
  red[ml][rq][kc][1] = a1;
  red[ml][rq][kc][2] = a2;
  red[ml][rq][kc][3] = a3;
  __syncthreads();
  if (t < 64) {
    const int ml2 = t >> 5, r = t & 31, rq2 = r >> 2, j = r & 3;
    float s = 0.f;
#pragma unroll
    for (int c = 0; c < 16; ++c) s += red[ml2][rq2][c][j];
    lact[(size_t)(blockIdx.x * 2 + ml2) * RK + r] = s;
  }
}

// ---------------------------------------------------------------------------
// k_prep: smooth + per-group int4 quantize.
//   scp3[(h*NG+g)*256 + ml]       = ascale           (h=m>>7, ml=m&127)
//   scp3[(h*NG+g)*256 + 128 + ml] = 8*(sum q)*ascale
//   wsA8[(MT*NG+g)*64+l] = 16 i8: q[m=MT*16+(l&15)][k=(l>>4)*16+j]
// ---------------------------------------------------------------------------
__global__ __launch_bounds__(256) void k_prep(const float* __restrict__ x,
                                              const float* __restrict__ smooth,
                                              float* __restrict__ scp3,
                                              i32x4* __restrict__ wsA8) {
  const int t    = threadIdx.x;
  const int ml   = t & 15;
  const int gl   = t >> 4;
  const int MT   = blockIdx.x >> 3;
  const int gblk = blockIdx.x & 7;
  const int m = MT * 16 + ml;
  const int g = gblk * 16 + gl;
  const float* xp = x + (size_t)m * C_DIM + g * 64;
  const float* sp = smooth + g * 64;
  float xs[64];
  float amax = 0.0f;
#pragma unroll
  for (int i = 0; i < 64; i += 4) {
    float4 xv = *(const float4*)(xp + i);
    float4 sv = *(const float4*)(sp + i);
    xs[i + 0] = xv.x / sv.x;
    xs[i + 1] = xv.y / sv.y;
    xs[i + 2] = xv.z / sv.z;
    xs[i + 3] = xv.w / sv.w;
    amax = fmaxf(amax, fabsf(xs[i + 0]));
    amax = fmaxf(amax, fabsf(xs[i + 1]));
    amax = fmaxf(amax, fabsf(xs[i + 2]));
    amax = fmaxf(amax, fabsf(xs[i + 3]));
  }
  const float ascale = fmaxf(amax / 7.0f, 1e-8f);
  int qi[64];
  int rs = 0;
#pragma unroll
  for (int i = 0; i < 64; ++i) {
    float qv = fminf(fmaxf(rintf(xs[i] / ascale), -8.0f), 7.0f);
    qi[i] = (int)qv;
    rs += qi[i];
  }
  const int h = m >> 7, mll = m & 127;
  scp3[((size_t)h * NG + g) * 256 + mll]       = ascale;
  scp3[((size_t)h * NG + g) * 256 + 128 + mll] = 8.0f * (float)rs * ascale;
  const size_t base = ((size_t)(MT * NG + g)) * 64;
#pragma unroll
  for (int lg = 0; lg < 4; ++lg) {
    const int* q = qi + lg * 16;
    i32x4 c;
#pragma unroll
    for (int dw = 0; dw < 4; ++dw)
      c[dw] = (q[dw * 4 + 0] & 0xff) | ((q[dw * 4 + 1] & 0xff) << 8) |
              ((q[dw * 4 + 2] & 0xff) << 16) | (q[dw * 4 + 3] << 24);
    wsA8[base + lg * 16 + ml] = c;
  }
}

// ---------------------------------------------------------------------------
// k_main: 1024 blocks x 256 thr (4 waves) = 4 blocks/CU, 4 waves/SIMD.
// Block: mhalf = bid&1 (128 m rows), n0 = (bid>>1)*16. Wave w: m-tiles
// {2w, 2w+1} local. Depth-3 software pipeline, uniform vmcnt(8) per iter:
// each iter issues exactly 4 vm-ops for group G+3 {B dwordx4->VGPR,
// SC gll4, A dwordx4 x2}. B packed-at-stage (3 VALU + ds_write_b32) into a
// 1KB/slot depth-4 ring; wave fragment = one swizzled ds_read_b128.
// ---------------------------------------------------------------------------
__global__ __launch_bounds__(256, 4) void k_main(
    const int* __restrict__ qw, const float* __restrict__ wsc,
    const float* __restrict__ pu, const float* __restrict__ bias,
    const float* __restrict__ scp3, const i32x4* __restrict__ wsA8,
    const float* __restrict__ lact, float* __restrict__ out) {
  const int t    = threadIdx.x;
  const int bid  = blockIdx.x;
  const int mh   = bid & 1;
  const int n0   = (bid >> 1) * 16;
  const int w    = t >> 6;
  const int l    = t & 63;
  const int lrow = l >> 4;
  const int lcol = l & 15;

  __shared__ int   ldsBf[4 * 256];    // packed-B ring, 4 x 1KB
  __shared__ float ldsSCf[4 * 256];   // SC ring {as128, rs128}, 4 x 1KB
  __shared__ float ldsW[NG * 16];     // 8KB wscale table

  // one-time wscale table
  for (int i = t; i < NG * 16; i += 256)
    ldsW[i] = wsc[(size_t)(i >> 4) * O_DIM + n0 + (i & 15)];

  // B staging: thread t loads row sr, chunk cg (4 ints = 4 k-values),
  // packs to 1 dword, writes quad-swizzled slot index.
  const int sr = t >> 4, cg = t & 15;
  const int* gB = qw + (size_t)(n0 + sr) * C_DIM + cg * 4;
  const int pwIdx = sr * 16 + (((cg >> 2) ^ ((sr >> 1) & 3)) << 2) + (cg & 3);
  // B fragment read: row lcol, quad lrow (swizzled) -> one b128
  const int rdIdx = lcol * 16 + ((lrow ^ ((lcol >> 1) & 3)) << 2);

  const float* gSC = scp3 + ((size_t)mh * NG) * 256 + t;
  const i32x4* gA0 = wsA8 + ((size_t)(mh * 8 + w * 2 + 0) * NG) * 64 + l;
  const i32x4* gA1 = wsA8 + ((size_t)(mh * 8 + w * 2 + 1) * NG) * 64 + l;

  const int scBase = w * 32 + lrow * 4;   // as row-base for mi=0

  __syncthreads();   // ldsW ready; vm/lgkm drained -> clean ledger

  i32x4 bR0, bR1, bR2, bR3;
  i32x4 A0_0, A0_1, A1_0, A1_1, A2_0, A2_1, A3_0, A3_1;

  // prologue: batches for g = 0,1,2 (fenced so batch order is preserved)
  bR0 = *(const i32x4*)(gB);
  gll4(gSC, &ldsSCf[0 * 256 + t]);
  A0_0 = gA0[0];
  A0_1 = gA1[0];
  asm volatile("" ::: "memory");
  bR1 = *(const i32x4*)(gB + 64);
  gll4(gSC + 256, &ldsSCf[1 * 256 + t]);
  A1_0 = gA0[64];
  A1_1 = gA1[64];
  asm volatile("" ::: "memory");
  bR2 = *(const i32x4*)(gB + 128);
  gll4(gSC + 512, &ldsSCf[2 * 256 + t]);
  A2_0 = gA0[128];
  A2_1 = gA1[128];

  f32x4 acc0 = (f32x4){0.f, 0.f, 0.f, 0.f};
  f32x4 acc1 = (f32x4){0.f, 0.f, 0.f, 0.f};
  const i32x4 z = (i32x4){0, 0, 0, 0};

#define BODY(U, UP3, G)                                                        \
  {                                                                            \
    asm volatile("s_waitcnt vmcnt(8) lgkmcnt(0)" ::: "memory");                \
    int pk = (bR##U[0] & 0xff) | ((bR##U[1] & 0xff) << 8) |                    \
             ((bR##U[2] & 0xff) << 16) | (bR##U[3] << 24);                     \
    ldsBf[(U) * 256 + pwIdx] = pk;                                             \
    asm volatile("s_waitcnt lgkmcnt(0)" ::: "memory");                         \
    __builtin_amdgcn_s_barrier();                                              \
    i32x4 bf = *(const i32x4*)&ldsBf[(U) * 256 + rdIdx];                       \
    f32x4 as0 = *(const f32x4*)&ldsSCf[(U) * 256 + scBase];                    \
    f32x4 rs0 = *(const f32x4*)&ldsSCf[(U) * 256 + scBase + 128];              \
    f32x4 as1 = *(const f32x4*)&ldsSCf[(U) * 256 + scBase + 16];               \
    f32x4 rs1 = *(const f32x4*)&ldsSCf[(U) * 256 + scBase + 144];              \
    const float wsv = ldsW[(G) * 16 + lcol];                                   \
    {                                                                          \
      int g3 = (G) + 3;                                                        \
      if (g3 > NG - 1) g3 = NG - 1;                                            \
      bR##UP3 = *(const i32x4*)(gB + (size_t)g3 * 64);                         \
      gll4(gSC + (size_t)g3 * 256, &ldsSCf[(UP3) * 256 + t]);                  \
      A##UP3##_0 = gA0[(size_t)g3 * 64];                                       \
      A##UP3##_1 = gA1[(size_t)g3 * 64];                                       \
    }                                                                          \
    i32x4 d0 = __builtin_amdgcn_mfma_i32_16x16x64_i8(A##U##_0, bf, z, 0, 0, 0);\
    i32x4 d1 = __builtin_amdgcn_mfma_i32_16x16x64_i8(A##U##_1, bf, z, 0, 0, 0);\
    f32x4 df0, df1;                                                            \
    df0[0] = (float)d0[0]; df0[1] = (float)d0[1];                              \
    df0[2] = (float)d0[2]; df0[3] = (float)d0[3];                              \
    df1[0] = (float)d1[0]; df1[1] = (float)d1[1];                              \
    df1[2] = (float)d1[2]; df1[3] = (float)d1[3];                              \
    acc0 += wsv * (as0 * df0 - rs0);                                           \
    acc1 += wsv * (as1 * df1 - rs1);                                           \
  }

  for (int p = 0; p < NG / 4; ++p) {
    const int g0 = p * 4;
    BODY(0, 3, g0 + 0)
    BODY(1, 0, g0 + 1)
    BODY(2, 1, g0 + 2)
    BODY(3, 2, g0 + 3)
  }
#undef BODY

  // epilogue: + bias + lora
  const int n = n0 + lcol;
  const float bv = bias[n];
  float4 puq[8];
#pragma unroll
  for (int rq = 0; rq < 8; ++rq)
    puq[rq] = *(const float4*)(pu + (size_t)n * RK + rq * 4);
#pragma unroll
  for (int mi = 0; mi < 2; ++mi) {
    const f32x4 av = (mi == 0) ? acc0 : acc1;
#pragma unroll
    for (int j = 0; j < 4; ++j) {
      const int m = mh * 128 + (w * 2 + mi) * 16 + lrow * 4 + j;
      const float* lp = lact + (size_t)m * RK;
      float lo = 0.f;
#pragma unroll
      for (int rq = 0; rq < 8; ++rq) {
        float4 lv = *(const float4*)(lp + rq * 4);
        lo += lv.x * puq[rq].x + lv.y * puq[rq].y + lv.z * puq[rq].z +
              lv.w * puq[rq].w;
      }
      out[(size_t)m * O_DIM + n] = av[j] + bv + lo;
    }
  }
}

// ---------------------------------------------------------------------------
extern "C" void kernel_launch(void* const* d_in, const int* in_sizes, int n_in,
                              void* d_out, int out_size, void* d_ws,
                              size_t ws_size, hipStream_t stream) {
  const float* x      = (const float*)d_in[0];
  const int*   qw     = (const int*)d_in[1];
  const float* wsc    = (const float*)d_in[2];
  const float* smooth = (const float*)d_in[3];
  const float* pd     = (const float*)d_in[4];
  const float* pu     = (const float*)d_in[5];
  const float* bias   = (const float*)d_in[6];
  float* out = (float*)d_out;

  char* ws = (char*)d_ws;
  float* lact = (float*)ws;                     // 32 KB
  float* scp3 = (float*)(ws + 32 * 1024);       // 2*128*256*4 = 256 KB
  i32x4* wsA8 = (i32x4*)(ws + 288 * 1024);      // 2 MB i8 A-fragments

  hipLaunchKernelGGL(k_prep, dim3(128), dim3(256), 0, stream, x, smooth, scp3,
                     wsA8);
  hipLaunchKernelGGL(k_lora, dim3(128), dim3(256), 0, stream, x, pd, lact);
  hipLaunchKernelGGL(k_main, dim3(1024), dim3(256), 0, stream, qw, wsc, pu,
                     bias, scp3, wsA8, lact, out);
}

// Round 8
// 163.488 us; speedup vs baseline: 1.1743x; 1.1743x over previous
//
#include <hip/hip_runtime.h>
#include <stdint.h>

#define C_DIM 8192
#define O_DIM 8192
#define M_DIM 256
#define NG    128     // C/64 groups
#define RK    32
#define SUPS  16      // super-iterations
#define GPS   8       // groups per super-iteration (512 k, 2KB/row)

typedef float f32x4 __attribute__((ext_vector_type(4)));
typedef int   i32x4 __attribute__((ext_vector_type(4)));
typedef unsigned int u32;

__device__ __forceinline__ void gll16(const void* g, void* l) {
  __builtin_amdgcn_global_load_lds(
      (const __attribute__((address_space(1))) void*)g,
      (__attribute__((address_space(3))) void*)l, 16, 0, 0);
}
__device__ __forceinline__ int pack8(i32x4 r) {
  return (r[0] & 0xff) | ((r[1] & 0xff) << 8) | ((r[2] & 0xff) << 16) |
         (r[3] << 24);
}

// ---------------------------------------------------------------------------
// k_lora: lact[m][r] = sum_k x[m][k] * pd[k][r]   (256 x 32, f32)
// ---------------------------------------------------------------------------
__global__ __launch_bounds__(256) void k_lora(const float* __restrict__ x,
                                              const float* __restrict__ pd,
                                              float* __restrict__ lact) {
  const int t  = threadIdx.x;
  const int rq = t & 7;           // r-quad fastest -> coalesced pd
  const int kc = (t >> 3) & 15;
  const int ml = t >> 7;
  const int m  = blockIdx.x * 2 + ml;
  const float* xrow = x + (size_t)m * C_DIM + kc * 512;
  const float* pdp  = pd + (size_t)(kc * 512) * RK + rq * 4;
  float a0 = 0.f, a1 = 0.f, a2 = 0.f, a3 = 0.f;
  for (int k = 0; k < 512; k += 4) {
    float4 xv = *(const float4*)(xrow + k);
    float4 p0 = *(const float4*)(pdp + (size_t)(k + 0) * RK);
    float4 p1 = *(const float4*)(pdp + (size_t)(k + 1) * RK);
    float4 p2 = *(const float4*)(pdp + (size_t)(k + 2) * RK);
    float4 p3 = *(const float4*)(pdp + (size_t)(k + 3) * RK);
    a0 += xv.x * p0.x + xv.y * p1.x + xv.z * p2.x + xv.w * p3.x;
    a1 += xv.x * p0.y + xv.y * p1.y + xv.z * p2.y + xv.w * p3.y;
    a2 += xv.x * p0.z + xv.y * p1.z + xv.z * p2.z + xv.w * p3.z;
    a3 += xv.x * p0.w + xv.y * p1.w + xv.z * p2.w + xv.w * p3.w;
  }
  __shared__ float red[2][8][16][4];
  red[ml][rq][kc][0] = a0;
  red[ml][rq][kc][1] = a1;
  red[ml][rq][kc][2] = a2;
  red[ml][rq][kc][3] = a3;
  __syncthreads();
  if (t < 64) {
    const int ml2 = t >> 5, r = t & 31, rq2 = r >> 2, j = r & 3;
    float s = 0.f;
#pragma unroll
    for (int c = 0; c < 16; ++c) s += red[ml2][rq2][c][j];
    lact[(size_t)(blockIdx.x * 2 + ml2) * RK + r] = s;
  }
}

// ---------------------------------------------------------------------------
// k_prep: smooth + per-group int4 quantize.
//   scp[g*512 + m]       = ascale
//   scp[g*512 + 256 + m] = 8*(sum q)*ascale
//   wsA8[(MT*NG+g)*64+l] = 16 i8: q[m=MT*16+(l&15)][k=(l>>4)*16+j]
// ---------------------------------------------------------------------------
__global__ __launch_bounds__(256) void k_prep(const float* __restrict__ x,
                                              const float* __restrict__ smooth,
                                              float* __restrict__ scp,
                                              i32x4* __restrict__ wsA8) {
  const int t    = threadIdx.x;
  const int ml   = t & 15;
  const int gl   = t >> 4;
  const int MT   = blockIdx.x >> 3;
  const int gblk = blockIdx.x & 7;
  const int m = MT * 16 + ml;
  const int g = gblk * 16 + gl;
  const float* xp = x + (size_t)m * C_DIM + g * 64;
  const float* sp = smooth + g * 64;
  float xs[64];
  float amax = 0.0f;
#pragma unroll
  for (int i = 0; i < 64; i += 4) {
    float4 xv = *(const float4*)(xp + i);
    float4 sv = *(const float4*)(sp + i);
    xs[i + 0] = xv.x / sv.x;
    xs[i + 1] = xv.y / sv.y;
    xs[i + 2] = xv.z / sv.z;
    xs[i + 3] = xv.w / sv.w;
    amax = fmaxf(amax, fabsf(xs[i + 0]));
    amax = fmaxf(amax, fabsf(xs[i + 1]));
    amax = fmaxf(amax, fabsf(xs[i + 2]));
    amax = fmaxf(amax, fabsf(xs[i + 3]));
  }
  const float ascale = fmaxf(amax / 7.0f, 1e-8f);
  int qi[64];
  int rs = 0;
#pragma unroll
  for (int i = 0; i < 64; ++i) {
    float qv = fminf(fmaxf(rintf(xs[i] / ascale), -8.0f), 7.0f);
    qi[i] = (int)qv;
    rs += qi[i];
  }
  scp[(size_t)g * 512 + m]       = ascale;
  scp[(size_t)g * 512 + 256 + m] = 8.0f * (float)rs * ascale;
  const size_t base = ((size_t)(MT * NG + g)) * 64;
#pragma unroll
  for (int lg = 0; lg < 4; ++lg) {
    const int* q = qi + lg * 16;
    i32x4 c;
#pragma unroll
    for (int dw = 0; dw < 4; ++dw)
      c[dw] = (q[dw * 4 + 0] & 0xff) | ((q[dw * 4 + 1] & 0xff) << 8) |
              ((q[dw * 4 + 2] & 0xff) << 16) | (q[dw * 4 + 3] << 24);
    wsA8[base + lg * 16 + ml] = c;
  }
}

// ---------------------------------------------------------------------------
// k_main: 512 blocks x 512 thr (8 waves), 2 blocks/CU. Block = 16 n x 256 m.
// Super-iterations of 8 groups: each qweight row advances 2KB contiguously
// per sup (kills DRAM stream thrash). B reg-staged -> packed i8 -> swizzled
// LDS dbuf; SC via 2x global_load_lds dbuf; A depth-4 register ring with
// exact counted vmcnt (12/6, sup-end 8; never drained in loop). One barrier
// per sup (16 total vs 128 in R7).
// ---------------------------------------------------------------------------
__global__ __launch_bounds__(512, 4) void k_main(
    const int* __restrict__ qw, const float* __restrict__ wsc,
    const float* __restrict__ pu, const float* __restrict__ bias,
    const float* __restrict__ scp, const i32x4* __restrict__ wsA8,
    const float* __restrict__ lact, float* __restrict__ out) {
  const int t    = threadIdx.x;
  const int n0   = blockIdx.x * 16;
  const int w    = t >> 6;
  const int l    = t & 63;
  const int lrow = l >> 4;
  const int lcol = l & 15;

  __shared__ char  ldsB[2][16][512];   // packed-B dbuf, 8KB each
  __shared__ float ldsSC[2][4096];     // {as256,rs256} x 8 groups, 16KB each
  __shared__ float ldsW[NG * 16];      // 8KB wscale table

  for (int i = t; i < NG * 16; i += 512)
    ldsW[i] = wsc[(size_t)(i >> 4) * O_DIM + n0 + (i & 15)];

  // B staging: thread (sr = t>>5 row, cg = t&31) loads 16 contiguous ints
  // (64B raw) -> packs to 16B -> one swizzled ds_write_b128.
  const int sr = t >> 5, cg = t & 31;
  const int* gB = qw + (size_t)(n0 + sr) * C_DIM + cg * 16;
  const int wslot = (cg ^ (sr & 7)) * 16;          // byte offset in row
  const char* gSCb = (const char*)scp;             // + s*16384 + t*16
  const i32x4* gA0 = wsA8 + ((size_t)(w * 2 + 0) * NG) * 64 + l;
  const i32x4* gA1 = wsA8 + ((size_t)(w * 2 + 1) * NG) * 64 + l;

  f32x4 acc0 = (f32x4){0.f, 0.f, 0.f, 0.f};
  f32x4 acc1 = (f32x4){0.f, 0.f, 0.f, 0.f};
  const i32x4 z = (i32x4){0, 0, 0, 0};

  i32x4 br0, br1, br2, br3;            // raw B chunks (next sup)
  i32x4 R0_0, R0_1, R1_0, R1_1, R2_0, R2_1, R3_0, R3_1;  // A ring (4 groups)

  __syncthreads();   // ldsW visible; vm/lgkm drained -> clean ledger

  // --- prologue: stage sup0 ---
  br0 = __builtin_nontemporal_load((const i32x4*)(gB + 0));
  br1 = __builtin_nontemporal_load((const i32x4*)(gB + 4));
  br2 = __builtin_nontemporal_load((const i32x4*)(gB + 8));
  br3 = __builtin_nontemporal_load((const i32x4*)(gB + 12));
  gll16(gSCb + t * 16, &ldsSC[0][t * 4]);
  gll16(gSCb + 8192 + t * 16, &ldsSC[0][2048 + t * 4]);
  R0_0 = gA0[0 * 64];  R0_1 = gA1[0 * 64];
  R1_0 = gA0[1 * 64];  R1_1 = gA1[1 * 64];
  R2_0 = gA0[2 * 64];  R2_1 = gA1[2 * 64];
  R3_0 = gA0[3 * 64];  R3_1 = gA1[3 * 64];
  asm volatile("s_waitcnt vmcnt(8)" ::: "memory");   // retire braw+gll
  {
    i32x4 pk = (i32x4){pack8(br0), pack8(br1), pack8(br2), pack8(br3)};
    *(i32x4*)&ldsB[0][sr][wslot] = pk;
  }
  asm volatile("s_waitcnt lgkmcnt(0)" ::: "memory");
  __builtin_amdgcn_s_barrier();

#define SUBJ(J, RA, RB, VMC)                                                   \
  {                                                                            \
    asm volatile("s_waitcnt vmcnt(" #VMC ")" ::: "memory");                    \
    i32x4 bf = *(const i32x4*)&ldsB[s & 1][lcol]                               \
                   [(((J) * 4 + lrow) ^ (lcol & 7)) * 16];                     \
    f32x4 as0 = *(const f32x4*)&ldsSC[s & 1][(J) * 512 + (w * 2 + 0) * 16 +    \
                                             lrow * 4];                        \
    f32x4 rs0 = *(const f32x4*)&ldsSC[s & 1][(J) * 512 + 256 +                 \
                                             (w * 2 + 0) * 16 + lrow * 4];     \
    f32x4 as1 = *(const f32x4*)&ldsSC[s & 1][(J) * 512 + (w * 2 + 1) * 16 +    \
                                             lrow * 4];                        \
    f32x4 rs1 = *(const f32x4*)&ldsSC[s & 1][(J) * 512 + 256 +                 \
                                             (w * 2 + 1) * 16 + lrow * 4];     \
    const float wsv = ldsW[(s * GPS + (J)) * 16 + lcol];                       \
    i32x4 d0 = __builtin_amdgcn_mfma_i32_16x16x64_i8(RA, bf, z, 0, 0, 0);      \
    i32x4 d1 = __builtin_amdgcn_mfma_i32_16x16x64_i8(RB, bf, z, 0, 0, 0);      \
    int gn = s * GPS + (J) + 4;                                                \
    if (gn > NG - 1) gn = NG - 1;                                              \
    RA = gA0[(size_t)gn * 64];                                                 \
    RB = gA1[(size_t)gn * 64];                                                 \
    f32x4 df0, df1;                                                            \
    df0[0] = (float)d0[0]; df0[1] = (float)d0[1];                              \
    df0[2] = (float)d0[2]; df0[3] = (float)d0[3];                              \
    df1[0] = (float)d1[0]; df1[1] = (float)d1[1];                              \
    df1[2] = (float)d1[2]; df1[3] = (float)d1[3];                              \
    acc0 += wsv * (as0 * df0 - rs0);                                           \
    acc1 += wsv * (as1 * df1 - rs1);                                           \
  }

  for (int s = 0; s < SUPS; ++s) {
    // top staging for sup s+1 (6 vm-ops; clamped reload for s=15)
    const int sn = (s < SUPS - 1) ? s + 1 : SUPS - 1;
    const int nb = (s + 1) & 1;
    br0 = __builtin_nontemporal_load((const i32x4*)(gB + sn * 512 + 0));
    br1 = __builtin_nontemporal_load((const i32x4*)(gB + sn * 512 + 4));
    br2 = __builtin_nontemporal_load((const i32x4*)(gB + sn * 512 + 8));
    br3 = __builtin_nontemporal_load((const i32x4*)(gB + sn * 512 + 12));
    gll16(gSCb + (size_t)sn * 16384 + t * 16, &ldsSC[nb][t * 4]);
    gll16(gSCb + (size_t)sn * 16384 + 8192 + t * 16, &ldsSC[nb][2048 + t * 4]);

    SUBJ(0, R0_0, R0_1, 12)
    SUBJ(1, R1_0, R1_1, 12)
    SUBJ(2, R2_0, R2_1, 12)
    SUBJ(3, R3_0, R3_1, 12)
    SUBJ(4, R0_0, R0_1, 6)
    SUBJ(5, R1_0, R1_1, 6)
    SUBJ(6, R2_0, R2_1, 6)
    SUBJ(7, R3_0, R3_1, 6)

    // end-of-sup: braw(s+1)+SC(s+1) already retired (j=4's vmcnt(6));
    // keep a safety wait, pack, publish, sync.
    asm volatile("s_waitcnt vmcnt(8)" ::: "memory");
    i32x4 pk = (i32x4){pack8(br0), pack8(br1), pack8(br2), pack8(br3)};
    *(i32x4*)&ldsB[nb][sr][wslot] = pk;
    asm volatile("s_waitcnt lgkmcnt(0)" ::: "memory");
    __builtin_amdgcn_s_barrier();
  }
#undef SUBJ

  // epilogue: + bias + lora
  const int n = n0 + lcol;
  const float bv = bias[n];
  float4 puq[8];
#pragma unroll
  for (int rq = 0; rq < 8; ++rq)
    puq[rq] = *(const float4*)(pu + (size_t)n * RK + rq * 4);
#pragma unroll
  for (int mi = 0; mi < 2; ++mi) {
    const f32x4 av = (mi == 0) ? acc0 : acc1;
#pragma unroll
    for (int j = 0; j < 4; ++j) {
      const int m = (w * 2 + mi) * 16 + lrow * 4 + j;
      const float* lp = lact + (size_t)m * RK;
      float lo = 0.f;
#pragma unroll
      for (int rq = 0; rq < 8; ++rq) {
        float4 lv = *(const float4*)(lp + rq * 4);
        lo += lv.x * puq[rq].x + lv.y * puq[rq].y + lv.z * puq[rq].z +
              lv.w * puq[rq].w;
      }
      out[(size_t)m * O_DIM + n] = av[j] + bv + lo;
    }
  }
}

// ---------------------------------------------------------------------------
extern "C" void kernel_launch(void* const* d_in, const int* in_sizes, int n_in,
                              void* d_out, int out_size, void* d_ws,
                              size_t ws_size, hipStream_t stream) {
  const float* x      = (const float*)d_in[0];
  const int*   qw     = (const int*)d_in[1];
  const float* wsc    = (const float*)d_in[2];
  const float* smooth = (const float*)d_in[3];
  const float* pd     = (const float*)d_in[4];
  const float* pu     = (const float*)d_in[5];
  const float* bias   = (const float*)d_in[6];
  float* out = (float*)d_out;

  char* ws = (char*)d_ws;
  float* lact = (float*)ws;                     // 32 KB
  float* scp  = (float*)(ws + 32 * 1024);       // 128*512*4 = 256 KB
  i32x4* wsA8 = (i32x4*)(ws + 288 * 1024);      // 2 MB i8 A-fragments

  hipLaunchKernelGGL(k_prep, dim3(128), dim3(256), 0, stream, x, smooth, scp,
                     wsA8);
  hipLaunchKernelGGL(k_lora, dim3(128), dim3(256), 0, stream, x, pd, lact);
  hipLaunchKernelGGL(k_main, dim3(512), dim3(512), 0, stream, qw, wsc, pu,
                     bias, scp, wsA8, lact, out);
}